// Round 1
// baseline (441.076 us; speedup 1.0000x reference)
//
#include <hip/hip_runtime.h>

// SlideSum: out = sliding_window_sum_3(x) * alpha, with y-row edge replication.
// x: (64, 4096, 256) fp32; alpha: scalar fp32; out: (64, 4096, 256) fp32.
//
// out[b, 0]    = (x[b,0]+x[b,1]+x[b,2]) * alpha
// out[b, l]    = (x[b,l-1]+x[b,l]+x[b,l+1]) * alpha     for 1 <= l <= 4094
// out[b, 4095] = (x[b,4093]+x[b,4094]+x[b,4095]) * alpha
//
// Strategy: one wave per (batch, L-chunk). Lane i holds the float4 covering
// features 4i..4i+3 (64 lanes x 16B = one full 1KiB row, perfectly coalesced).
// Sliding 3-row register window: exactly 1 load + 1 store per output row.

#define BB    64
#define LL    4096
#define F4    64      // 256 floats as float4
#define NOUT  4094    // L - WINDOW + 1
#define CHUNK 32      // y-rows per wave-task
#define NCHUNK 128    // ceil(NOUT / CHUNK) -> 128 (last chunk partial: 30 rows)

__global__ __launch_bounds__(256) void
slide_sum_kernel(const float4* __restrict__ x,
                 const float* __restrict__ alpha_p,
                 float4* __restrict__ out) {
    const float alpha = *alpha_p;

    const int lane  = threadIdx.x & 63;
    const int wave  = threadIdx.x >> 6;
    const int task  = blockIdx.x * 4 + wave;   // 0 .. 8191
    const int b     = task >> 7;               // task / NCHUNK
    const int chunk = task & (NCHUNK - 1);

    const int y0 = chunk * CHUNK;
    int yend = y0 + CHUNK;
    if (yend > NOUT) yend = NOUT;
    if (y0 >= NOUT) return;

    const float4* xb = x   + (size_t)b * LL * F4 + lane;
    float4*       ob = out + (size_t)b * LL * F4 + lane;

    float4 s0 = xb[(size_t)y0 * F4];
    float4 s1 = xb[(size_t)(y0 + 1) * F4];

    #pragma unroll 8
    for (int y = y0; y < yend; ++y) {
        float4 s2 = xb[(size_t)(y + 2) * F4];
        float4 r;
        r.x = (s0.x + s1.x + s2.x) * alpha;
        r.y = (s0.y + s1.y + s2.y) * alpha;
        r.z = (s0.z + s1.z + s2.z) * alpha;
        r.w = (s0.w + s1.w + s2.w) * alpha;
        ob[(size_t)(y + 1) * F4] = r;
        if (y == 0)        ob[0] = r;                       // replicate first y-row
        if (y == NOUT - 1) ob[(size_t)(LL - 1) * F4] = r;   // replicate last y-row
        s0 = s1;
        s1 = s2;
    }
}

extern "C" void kernel_launch(void* const* d_in, const int* in_sizes, int n_in,
                              void* d_out, int out_size, void* d_ws, size_t ws_size,
                              hipStream_t stream) {
    const float4* x       = (const float4*)d_in[0];
    const float*  alpha_p = (const float*)d_in[1];
    float4*       out     = (float4*)d_out;

    // 8192 wave-tasks (64 batches x 128 chunks), 4 waves per 256-thread block.
    const int blocks = (BB * NCHUNK) / 4;   // 2048
    slide_sum_kernel<<<blocks, 256, 0, stream>>>(x, alpha_p, out);
}

// Round 2
// 440.117 us; speedup vs baseline: 1.0022x; 1.0022x over previous
//
#include <hip/hip_runtime.h>

// SlideSum: out = sliding_window_sum_3(x) * alpha, with y-row edge replication.
// x: (64, 4096, 256) fp32 -> out same shape.
//
// out[b,l] = (x[b,c-1]+x[b,c]+x[b,c+1])*alpha, c = clamp(l, 1, 4094)
//
// R2 strategy: device-wide sequential front. Block k owns 16 CONSECUTIVE
// L-rows; consecutive blocks own consecutive memory, so at any instant the
// whole device streams one contiguous region (like the 6.5 TB/s fill kernel),
// instead of 8192 scattered per-wave streams (R1: 1.23 TB/s).
// Within a block: wave w slides a 3-row register window over rows
// [16k+4w .. 16k+4w+3] (6 loads -> 4 outputs). Lane i holds float4 f=4i..4i+3,
// so every load/store is one fully-coalesced 1 KiB wave transaction.
// Nontemporal stores: output is write-once, keep it out of L2 so the
// cross-block boundary-row read reuse stays cached.

typedef float v4f __attribute__((ext_vector_type(4)));

#define BB   64
#define LL   4096
#define F4   64     // 256 floats = 64 float4 per row
#define RPB  16     // L-rows per block (4 per wave)

__global__ __launch_bounds__(256) void
slide_sum_kernel(const float4* __restrict__ x,
                 const float* __restrict__ alpha_p,
                 float4* __restrict__ out) {
    const float alpha = *alpha_p;

    const int lane = threadIdx.x & 63;
    const int wave = threadIdx.x >> 6;
    const int b    = blockIdx.x >> 8;                      // 256 blocks per batch
    const int r0   = ((blockIdx.x & 255) << 4) + (wave << 2);  // first output row

    const float4* xb = x   + (size_t)b * LL * F4 + lane;
    float4*       ob = out + (size_t)b * LL * F4 + lane;

    // Output rows l in [lstart, lend] use window centered at c=l (interior).
    // Row 0 duplicates row 1's value; row 4095 duplicates row 4094's.
    const int lstart = (r0 < 1) ? 1 : r0;
    const int lend   = (r0 + 3 > 4094) ? 4094 : (r0 + 3);

    float4 s0 = xb[(lstart - 1) * F4];
    float4 s1 = xb[(lstart    ) * F4];

    #pragma unroll 4
    for (int l = lstart; l <= lend; ++l) {
        float4 s2 = xb[(l + 1) * F4];
        float4 r;
        r.x = (s0.x + s1.x + s2.x) * alpha;
        r.y = (s0.y + s1.y + s2.y) * alpha;
        r.z = (s0.z + s1.z + s2.z) * alpha;
        r.w = (s0.w + s1.w + s2.w) * alpha;
        __builtin_nontemporal_store(*(const v4f*)&r, (v4f*)(ob + l * F4));
        if (l == 1)    // first wave of each batch also writes replicated row 0
            __builtin_nontemporal_store(*(const v4f*)&r, (v4f*)ob);
        if (l == 4094) // last wave also writes replicated row 4095
            __builtin_nontemporal_store(*(const v4f*)&r, (v4f*)(ob + (LL - 1) * F4));
        s0 = s1;
        s1 = s2;
    }
}

extern "C" void kernel_launch(void* const* d_in, const int* in_sizes, int n_in,
                              void* d_out, int out_size, void* d_ws, size_t ws_size,
                              hipStream_t stream) {
    const float4* x       = (const float4*)d_in[0];
    const float*  alpha_p = (const float*)d_in[1];
    float4*       out     = (float4*)d_out;

    const int blocks = BB * (LL / RPB);   // 64 * 256 = 16384
    slide_sum_kernel<<<blocks, 256, 0, stream>>>(x, alpha_p, out);
}